// Round 2
// baseline (658.037 us; speedup 1.0000x reference)
//
#include <hip/hip_runtime.h>
#include <hip/hip_bf16.h>
#include <stdint.h>

#define BATCH 128
#define SEQ   512
#define NW    6
#define DIM   64
#define NELEM (BATCH * SEQ * NW)   // 393216
#define PI_F  3.14159265358979323846f

// ---------------------------------------------------------------------------
// CNOT-chain gather permutations (wire 0 = MSB of the 6-bit index).
// g_{c,t}(i) = i ^ (bit_c(i) * m_t), bit_c at shift (5-c), m_t = 1<<(5-t).
// Gather composition: psi_final[i] = psi_0[g_first(...g_last(i)...)],
// so we evaluate the LAST-applied CNOT innermost.
// ---------------------------------------------------------------------------
__device__ __forceinline__ int Gq(int i) {          // C01,C12,C23,C34,C45,C50
    int x = i ^ ((i & 1) << 5);                     // g50 (last applied)
    x ^= (x >> 1) & 1;                              // g45
    x ^= ((x >> 2) & 1) << 1;                       // g34
    x ^= ((x >> 3) & 1) << 2;                       // g23
    x ^= ((x >> 4) & 1) << 3;                       // g12
    x ^= ((x >> 5) & 1) << 4;                       // g01
    return x;
}
__device__ __forceinline__ int Gv(int i) {          // C01,C12,C23,C34,C45
    int x = i ^ ((i >> 1) & 1);                     // g45 (last applied)
    x ^= ((x >> 2) & 1) << 1;                       // g34
    x ^= ((x >> 3) & 1) << 2;                       // g23
    x ^= ((x >> 4) & 1) << 3;                       // g12
    x ^= ((x >> 5) & 1) << 4;                       // g01
    return x;
}

// ---------------------------------------------------------------------------
// Kernel 1: detect whether float tensors are stored as bf16 or f32.
// Read first 256 u32 words of `angles` (safe under both interpretations:
// bf16 buffer = 196608 words). For bf16 data the LOW 16 bits of each word is
// itself a bf16 of U(0,pi): its exponent byte lands in [0x3A,0x41] almost
// surely. For f32 data the low 16 bits are mantissa noise (~3% hit rate).
// ---------------------------------------------------------------------------
__global__ void k_detect(const uint32_t* __restrict__ a, int* __restrict__ flag) {
    __shared__ int cnt;
    if (threadIdx.x == 0) cnt = 0;
    __syncthreads();
    uint32_t w = a[threadIdx.x];
    uint32_t e = (w >> 8) & 0xFFu;          // exponent byte of low-half bf16
    if (e >= 0x3Au && e <= 0x41u) atomicAdd(&cnt, 1);
    __syncthreads();
    if (threadIdx.x == 0) *flag = (cnt >= 128) ? 1 : 0;   // 1 = bf16
}

__device__ __forceinline__ float ldf(const void* p, int i, bool bf) {
    if (bf) {
        uint32_t u = (uint32_t)((const uint16_t*)p)[i];
        return __uint_as_float(u << 16);
    }
    return ((const float*)p)[i];
}

// ---------------------------------------------------------------------------
// Kernel 2: convert inputs to f32 in workspace; precompute cos/sin(x/2) for
// every injection angle at full device parallelism (removes 6 of 12 per-step
// transcendentals from the recurrent critical path).
// cs layout: [b][t][w][2] -> 12 consecutive floats per (b,t).
// misc: [0..3]=poly, [4..39]=fwd_params, [40..75]=bwd_params, [76]=fc, [77]=bc
// ---------------------------------------------------------------------------
__global__ void k_convert(const void* ang, const void* poly, const void* fp,
                          const void* bp, const void* fc, const void* bc,
                          float* __restrict__ cs, float* __restrict__ misc,
                          const int* __restrict__ flag) {
    const bool bf = (*flag != 0);
    const int i = blockIdx.x * blockDim.x + threadIdx.x;
    if (i < NELEM) {
        float x = ldf(ang, i, bf);
        float s, c;
        __sincosf(0.5f * x, &s, &c);
        cs[2 * i]     = c;
        cs[2 * i + 1] = s;
    }
    if (i < 4)                    misc[i]            = ldf(poly, i, bf);
    else if (i >= 64 && i < 100)  misc[4 + (i - 64)] = ldf(fp, i - 64, bf);
    else if (i >= 128 && i < 164) misc[40 + (i - 128)] = ldf(bp, i - 128, bf);
    else if (i == 200)            misc[76] = ldf(fc, 0, bf);
    else if (i == 201)            misc[77] = ldf(bc, 0, bf);
}

// ---------------------------------------------------------------------------
// Kernel 3: the recurrent simulation. One wave (64 threads) per chain;
// lane p holds one complex amplitude. All CNOT permutations are virtualized:
// lane p's value is the logical amplitude at index f(p), f GF(2)-linear.
//  f0=id, f_{d}=Gq^{-d} (QSVT stages), f5=Gv^{-1} f4, f6=Gv^{-1} f5.
//  - diagonal phase at stage d: per-lane constant from pop(f_d(p)); all four
//    stages fuse into ONE complex constant (Pc,Ps).
//  - gate on wire w at stage f: partner lane = p ^ f^{-1}(m_w) (uniform),
//    coefficient row chosen by bit_w(f(p)) (per-lane constant).
//  - measurement: WHT butterfly over lanes; <Z_w> sits at lane L_w = F^T m_w.
// ---------------------------------------------------------------------------
__global__ void __launch_bounds__(64) k_sim(const float* __restrict__ cs,
                                            const float* __restrict__ misc,
                                            float* __restrict__ hbuf) {
    const int p     = threadIdx.x;
    const int chain = blockIdx.x;            // 0..255
    const int dir   = chain >> 7;            // 0 = fwd, 1 = bwd
    const int b     = chain & 127;
    const float* poly = misc;
    const float* prm  = misc + (dir ? 40 : 4);
    float* orow = hbuf + (size_t)dir * NELEM + (size_t)b * (SEQ * NW);
    const float* csrow_base = cs + (size_t)b * (SEQ * NW * 2);

    // ---- permutation tables (setup only) ----
    __shared__ int GIQ[DIM], GIV[DIM];       // inverse gathers
    GIQ[Gq(p)] = p;
    GIV[Gv(p)] = p;
    __syncthreads();
    const int i1 = GIQ[p], i2 = GIQ[i1], i3 = GIQ[i2], i4 = GIQ[i3];
    const int i5 = GIV[i4], i6 = GIV[i5];

    // ---- fused QSVT phase constant ----
    float Pc = 1.f, Ps = 0.f;
    {
        int pops[4];
        pops[0] = (int)__popc((unsigned)p);
        pops[1] = (int)__popc((unsigned)i1);
        pops[2] = (int)__popc((unsigned)i2);
        pops[3] = (int)__popc((unsigned)i3);
#pragma unroll
        for (int d = 0; d < 4; ++d) {
            float ang = PI_F * poly[d] * (float)(pops[d] - 3);
            float s, c;
            __sincosf(ang, &s, &c);
            float nc = Pc * c - Ps * s;
            float ns = Pc * s + Ps * c;
            Pc = nc; Ps = ns;
        }
    }

    // ---- partner XOR masks (wave-uniform) ----
    int E[12], E3[6];
#pragma unroll
    for (int w = 0; w < NW; ++w) {
        const int m = 1 << (5 - w);
        E[w]     = Gq(Gq(Gq(Gq(m))));                 // f4^{-1}(m) = Gq^4
        E[6 + w] = Gq(Gq(Gq(Gq(Gv(m)))));             // f5^{-1} = Gq^4 . Gv
        E3[w]    = Gq(Gq(Gq(Gq(Gv(Gv(m))))));         // f6^{-1} = Gq^4 . Gv^2
    }

    // ---- per-lane gate coefficient rows: C1 = U[b][b], C2 = U[b][1-b] ----
    float C1r[12], C1i[12], C2r[12], C2i[12];
#pragma unroll
    for (int g = 0; g < 12; ++g) {
        const int layer = g / 6, w = g % 6;
        float cx, sx, cy, sy, cz, sz;
        __sincosf(0.5f * prm[3 * g + 0], &sx, &cx);   // RX angle (applied first)
        __sincosf(0.5f * prm[3 * g + 1], &sy, &cy);   // RY
        __sincosf(0.5f * prm[3 * g + 2], &sz, &cz);   // RZ (applied last)
        // U = RZ * RY * RX
        const float A = cy * cx, B = sy * sx, C = sy * cx, D = cy * sx;
        const float U00r = cz * A + sz * B, U00i = cz * B - sz * A;
        const float U11r = U00r,            U11i = sz * A - cz * B;
        const float Xr   = cz * C + sz * D, Xi   = sz * C - cz * D;
        // U01 = -Xr + i*Xi ; U10 = +Xr + i*Xi
        const int fi = (layer == 0) ? i4 : i5;
        const int bb = (fi >> (5 - w)) & 1;
        C1r[g] = bb ? U11r : U00r;
        C1i[g] = bb ? U11i : U00i;
        C2r[g] = bb ? Xr : -Xr;
        C2i[g] = Xi;
    }

    // ---- injection signs: b=1 -> +s*partner, b=0 -> -s*partner ----
    float SG[6];
#pragma unroll
    for (int w = 0; w < NW; ++w) SG[w] = ((i6 >> (5 - w)) & 1) ? 1.f : -1.f;

    // ---- measurement extraction lanes: L_w bit j = bit_w(f6(2^j)) ----
    int Lw[6] = {0, 0, 0, 0, 0, 0};
#pragma unroll
    for (int j = 0; j < 6; ++j) {
        const int f6x = GIV[GIV[GIQ[GIQ[GIQ[GIQ[1 << j]]]]]];
#pragma unroll
        for (int w = 0; w < NW; ++w)
            if ((f6x >> (5 - w)) & 1) Lw[w] |= (1 << j);
    }
    int myw = -1;
#pragma unroll
    for (int w = 0; w < NW; ++w)
        if (Lw[w] == p) myw = w;

    // ---- WHT butterfly signs ----
    float BS[6];
#pragma unroll
    for (int k = 0; k < 6; ++k) BS[k] = (p & (1 << k)) ? -1.f : 1.f;

    // ---- encode selection bits (f0 = identity) ----
    bool EB[6];
#pragma unroll
    for (int w = 0; w < NW; ++w) EB[w] = (p >> (5 - w)) & 1;

    // =======================  recurrent loop  =======================
    float h[6] = {0.f, 0.f, 0.f, 0.f, 0.f, 0.f};
    for (int t = 0; t < SEQ; ++t) {
        const int tin = dir ? (SEQ - 1 - t) : t;
        const float* xr = csrow_base + tin * (NW * 2);   // 12 uniform floats

        // 1) product-state encode  (+ fused QSVT phases: state real -> 2 muls)
        float amp = 1.f;
#pragma unroll
        for (int w = 0; w < NW; ++w) {
            float s, c;
            __sincosf(0.5f * h[w], &s, &c);
            amp *= EB[w] ? s : c;
        }
        float re = amp * Pc;
        float im = amp * Ps;

        // 2) variational layers: 12 fixed single-qubit gates (perms virtual)
#pragma unroll
        for (int g = 0; g < 12; ++g) {
            const float pr = __shfl_xor(re, E[g], 64);
            const float pi = __shfl_xor(im, E[g], 64);
            const float nr = C1r[g] * re - C1i[g] * im + C2r[g] * pr - C2i[g] * pi;
            const float ni = C1r[g] * im + C1i[g] * re + C2r[g] * pi + C2i[g] * pr;
            re = nr; im = ni;
        }

        // 3) per-batch RY injection (cos/sin precomputed in k_convert)
#pragma unroll
        for (int w = 0; w < NW; ++w) {
            const float cx = xr[2 * w];
            const float ss = SG[w] * xr[2 * w + 1];
            const float pr = __shfl_xor(re, E3[w], 64);
            const float pi = __shfl_xor(im, E3[w], 64);
            re = cx * re + ss * pr;
            im = cx * im + ss * pi;
        }

        // 4) measurement: WHT butterfly over lanes
        float q = re * re + im * im;
#pragma unroll
        for (int k = 0; k < 6; ++k) {
            const float o = __shfl_xor(q, 1 << k, 64);
            q = fmaf(BS[k], q, o);
        }

        // 5) store raw h for this step (6 designated lanes), feed next step
        if (myw >= 0) orow[tin * NW + myw] = q;
#pragma unroll
        for (int w = 0; w < NW; ++w) h[w] = __shfl(q, Lw[w], 64);
    }
}

// ---------------------------------------------------------------------------
// Kernel 4: out = sigmoid(fc)*h_fwd + sigmoid(bc)*h_bwd, dtype per flag.
// ---------------------------------------------------------------------------
__global__ void k_combine(const float* __restrict__ hbuf,
                          const float* __restrict__ misc,
                          void* __restrict__ out, const int* __restrict__ flag) {
    const int i = blockIdx.x * blockDim.x + threadIdx.x;
    if (i >= NELEM) return;
    const float sf = 1.f / (1.f + __expf(-misc[76]));
    const float sb = 1.f / (1.f + __expf(-misc[77]));
    const float v = sf * hbuf[i] + sb * hbuf[NELEM + i];
    if (*flag) ((__hip_bfloat16*)out)[i] = __float2bfloat16(v);
    else       ((float*)out)[i] = v;
}

// ---------------------------------------------------------------------------
extern "C" void kernel_launch(void* const* d_in, const int* in_sizes, int n_in,
                              void* d_out, int out_size, void* d_ws, size_t ws_size,
                              hipStream_t stream) {
    const void* ang  = d_in[0];
    const void* poly = d_in[1];
    const void* fp   = d_in[2];
    const void* bp   = d_in[3];
    const void* fc   = d_in[4];
    const void* bc   = d_in[5];

    // workspace layout (floats): cs[2*NELEM] | misc[128] | hbuf[2*NELEM] | flag
    float* cs   = (float*)d_ws;
    float* misc = cs + 2 * NELEM;
    float* hbuf = misc + 128;
    int*   flag = (int*)(hbuf + 2 * NELEM);
    // needed: (4*NELEM + 128)*4 + 4 ~= 6.3 MB of ws

    k_detect<<<1, 256, 0, stream>>>((const uint32_t*)ang, flag);
    k_convert<<<(NELEM + 255) / 256, 256, 0, stream>>>(ang, poly, fp, bp, fc, bc,
                                                       cs, misc, flag);
    k_sim<<<256, 64, 0, stream>>>(cs, misc, hbuf);
    k_combine<<<(NELEM + 255) / 256, 256, 0, stream>>>(hbuf, misc, d_out, flag);
}